// Round 7
// baseline (222.853 us; speedup 1.0000x reference)
//
#include <hip/hip_runtime.h>
#include <hip/hip_bf16.h>

// Problem constants (B=4, S=2048 -> 8192 tokens; D=O=1024; E=8; top-2)
#define NTOK 8192
#define DDIM 1024
#define ODIM 1024
#define NEXP 8
#define BK   32
#define NKT  (DDIM / BK)     // 32 K-tiles

typedef __attribute__((ext_vector_type(8))) short short8;
typedef __attribute__((ext_vector_type(4))) float f32x4;

// ---- workspace layout (bytes) ----
#define CNT_OFF   0u                               // 8 ints (per expert)
#define SC_OFF    (4u * 1024u)                     // 8192*2 floats
#define LIST_OFF  (128u * 1024u)                   // 8*8192 ints
#define XH_OFF    (1u << 20)                       // bf16 x, 16 MiB
#define WH_OFF    ((1u << 20) + 16u*1024u*1024u)   // bf16 W, 16 MiB

__device__ inline unsigned short f2bf(float f) {
    unsigned int u = __float_as_uint(f);
    unsigned int r = (u + 0x7FFFu + ((u >> 16) & 1u)) >> 16;   // RNE
    return (unsigned short)r;
}

__device__ inline void glds16(const unsigned short* g, unsigned short* l) {
    __builtin_amdgcn_global_load_lds(
        (const __attribute__((address_space(1))) unsigned int*)g,
        (__attribute__((address_space(3))) unsigned int*)l, 16, 0, 0);
}

// W fp32->bf16; block 0 also zeroes the per-expert counts (runs pre-gate)
__global__ void k_cvtw(const float4* __restrict__ src, ushort4* __restrict__ dst,
                       int n4, int* __restrict__ counts) {
    if (blockIdx.x == 0 && threadIdx.x < NEXP) counts[threadIdx.x] = 0;
    int i = blockIdx.x * blockDim.x + threadIdx.x;
    if (i >= n4) return;
    float4 v = src[i];
    ushort4 o;
    o.x = f2bf(v.x); o.y = f2bf(v.y); o.z = f2bf(v.z); o.w = f2bf(v.w);
    dst[i] = o;
}

// Gating: 1024 blocks x 8 tokens (2 per wave). No launch-bounds VGPR cap
// (round 5: forcing 128 VGPR spilled ~180MB scratch). fp64 dot+butterfly
// decides top-k; fp32 expf for weights. 8 expert lists (entry = t*2+rank),
// block-aggregated scatter. Fused: bf16 x, and out init = s0*b0 + s1*b1
// (gemm then pure-atomicAdd, no out2/k_add pass).
__global__ __launch_bounds__(256) void k_gate(
    const float* __restrict__ x, const float* __restrict__ Wg,
    const float* __restrict__ bg, const float* __restrict__ b,
    float* __restrict__ out, float* __restrict__ scores2,
    int* __restrict__ lists, int* __restrict__ counts,
    unsigned short* __restrict__ xh)
{
    __shared__ unsigned char s_eid[16];     // 8 tokens * 2 entries
    const int tid = threadIdx.x, wave = tid >> 6, lane = tid & 63;
    const int tblk = blockIdx.x * 8;

    #pragma unroll 1
    for (int ti = 0; ti < 2; ti++) {
        const int t = tblk + wave * 2 + ti;
        const float* xr = x + (size_t)t * DDIM;
        float4 xv[4];
        #pragma unroll
        for (int i = 0; i < 4; i++)
            xv[i] = *(const float4*)&xr[lane * 4 + 256 * i];

        unsigned short* xhr = xh + (size_t)t * DDIM;
        #pragma unroll
        for (int i = 0; i < 4; i++) {
            ushort4 h;
            h.x = f2bf(xv[i].x); h.y = f2bf(xv[i].y);
            h.z = f2bf(xv[i].z); h.w = f2bf(xv[i].w);
            *(ushort4*)&xhr[lane * 4 + 256 * i] = h;
        }

        double lg[NEXP];
        #pragma unroll
        for (int e = 0; e < NEXP; e++) {
            const float* wr = Wg + (size_t)e * DDIM;
            double a = 0.0;
            #pragma unroll
            for (int i = 0; i < 4; i++) {
                float4 wv = *(const float4*)&wr[lane * 4 + 256 * i];
                a += (double)xv[i].x * (double)wv.x + (double)xv[i].y * (double)wv.y
                   + (double)xv[i].z * (double)wv.z + (double)xv[i].w * (double)wv.w;
            }
            #pragma unroll
            for (int off = 32; off > 0; off >>= 1) a += __shfl_xor(a, off);
            lg[e] = a + (double)bg[e];
        }

        int i0 = -1, i1 = -1;
        double best = -1e300, sec = -1e300;
        #pragma unroll
        for (int e = 0; e < NEXP; e++) {
            double v = lg[e];
            if (v > best) { sec = best; i1 = i0; best = v; i0 = e; }
            else if (v > sec) { sec = v; i1 = e; }
        }
        float sum = 0.f;
        #pragma unroll
        for (int e = 0; e < NEXP; e++) sum += expf((float)(lg[e] - best));
        float s0 = 1.f / sum;
        float s1 = expf((float)(sec - best)) / sum;

        if (lane == 0) {
            scores2[t * 2 + 0] = s0;
            scores2[t * 2 + 1] = s1;
            int le = (wave * 2 + ti) * 2;
            s_eid[le + 0] = (unsigned char)i0;
            s_eid[le + 1] = (unsigned char)i1;
        }

        const float* b0 = b + (size_t)i0 * ODIM;
        const float* b1 = b + (size_t)i1 * ODIM;
        float* orow = out + (size_t)t * ODIM;
        #pragma unroll
        for (int i = 0; i < 4; i++) {
            int o = lane * 4 + 256 * i;
            float4 v0 = *(const float4*)&b0[o];
            float4 v1 = *(const float4*)&b1[o];
            float4 r;
            r.x = s0 * v0.x + s1 * v1.x;
            r.y = s0 * v0.y + s1 * v1.y;
            r.z = s0 * v0.z + s1 * v1.z;
            r.w = s0 * v0.w + s1 * v1.w;
            *(float4*)&orow[o] = r;
        }
    }
    __syncthreads();

    // 8 owners; one global atomic per (block, expert)
    if (tid < NEXP) {
        int c = 0;
        #pragma unroll
        for (int j = 0; j < 16; j++) c += (s_eid[j] == tid);
        if (c) {
            int p = atomicAdd(&counts[tid], c);
            #pragma unroll
            for (int j = 0; j < 16; j++)
                if (s_eid[j] == tid)
                    lists[tid * NTOK + (p++)] = (tblk + (j >> 1)) * 2 + (j & 1);
        }
    }
}

// Grouped GEMM, 128x128 tile, BK=32, 3-buffer LDS (48 KiB) with counted-vmcnt
// software pipeline (T3/T4): raw s_barrier, loads stay in flight across
// barriers (prefetch depth 2). Per K-step:
//   issue stage(t+2) -> s_waitcnt vmcnt(8) [t's loads done] -> s_barrier
//   -> ds_read/MFMA buf[t%3] -> s_barrier [frees buf for t+3].
// XOR seg-swizzle as before. Epilogue: atomicAdd (proven ~free in round 4);
// out was bias-initialized by k_gate.
#define WAITV(n) do { asm volatile("s_waitcnt vmcnt(" #n ")" ::: "memory"); \
                      __builtin_amdgcn_sched_barrier(0); } while (0)
#define BARR  do { __builtin_amdgcn_sched_barrier(0); \
                   __builtin_amdgcn_s_barrier(); \
                   __builtin_amdgcn_sched_barrier(0); } while (0)

__global__ __launch_bounds__(256) void k_gemm(
    const unsigned short* __restrict__ xh, const unsigned short* __restrict__ wh,
    const int* __restrict__ counts, const int* __restrict__ lists,
    const float* __restrict__ scores2, float* __restrict__ out)
{
    __shared__ __align__(16) unsigned short As[3][128 * BK];
    __shared__ __align__(16) unsigned short Bs[3][128 * BK];

    const int nwg = (int)gridDim.x;
    const int bid0 = ((int)blockIdx.x & 7) * (nwg >> 3) + ((int)blockIdx.x >> 3);
    const int tid = threadIdx.x, wid = tid >> 6, lane = tid & 63;

    int cnts[NEXP];
    #pragma unroll
    for (int i = 0; i < NEXP; i++) cnts[i] = counts[i];
    int tbTot = 0;
    #pragma unroll
    for (int i = 0; i < NEXP; i++) tbTot += ((cnts[i] + 127) >> 7) * 8;

    const int rl = lane >> 2;               // row-in-call
    const int wm = wid >> 1, wn = wid & 1;
    const int fr = lane & 15, g4 = lane >> 4;

    #pragma unroll 1
    for (int tile = bid0; tile < tbTot; tile += nwg) {
        // decode tile -> (expert e, m-tile, n-tile)
        int e = 0, base = 0, cnt = 0, acc_ = 0;
        #pragma unroll
        for (int i = 0; i < NEXP; i++) {
            int nt_ = ((cnts[i] + 127) >> 7) * 8;
            if (tile >= acc_) { e = i; base = acc_; cnt = cnts[i]; }
            acc_ += nt_;
        }
        const int local = tile - base, mt = local >> 3, ntc = local & 7;
        const int m0 = mt * 128, n0 = ntc * 128;
        const int* list = lists + e * NTOK;
        const unsigned short* whE = wh + (size_t)e * ODIM * DDIM;

        const unsigned short* aS[2];
        const unsigned short* bS[2];
        int rb[2];
        #pragma unroll
        for (int i = 0; i < 2; i++) {
            int R = wid * 32 + i * 16 + rl;
            int sl = (lane & 3) ^ ((R >> 1) & 3);       // inverse-swizzled seg
            int g = m0 + R; if (g >= cnt) g = cnt - 1;
            aS[i] = xh + (size_t)(list[g] >> 1) * DDIM + sl * 8;
            bS[i] = whE + (size_t)(n0 + R) * DDIM + sl * 8;
            rb[i] = (wid * 32 + i * 16) * BK;
        }

        f32x4 acc[4][4];
        #pragma unroll
        for (int m = 0; m < 4; m++)
            #pragma unroll
            for (int n = 0; n < 4; n++)
                acc[m][n] = (f32x4){0.f, 0.f, 0.f, 0.f};

        #define STAGE(kt, bi) do { const int k0_ = (kt) * BK;            \
            glds16(aS[0] + k0_, &As[bi][rb[0]]);                          \
            glds16(aS[1] + k0_, &As[bi][rb[1]]);                          \
            glds16(bS[0] + k0_, &Bs[bi][rb[0]]);                          \
            glds16(bS[1] + k0_, &Bs[bi][rb[1]]); } while (0)

        #define BODY(bi) do {                                             \
            short8 af[4], bf_[4];                                         \
            _Pragma("unroll")                                             \
            for (int m = 0; m < 4; m++) {                                 \
                int R = wm * 64 + m * 16 + fr;                            \
                int ph = g4 ^ ((R >> 1) & 3);                             \
                af[m] = *(const short8*)&As[bi][R * BK + ph * 8];         \
            }                                                             \
            _Pragma("unroll")                                             \
            for (int n = 0; n < 4; n++) {                                 \
                int R = wn * 64 + n * 16 + fr;                            \
                int ph = g4 ^ ((R >> 1) & 3);                             \
                bf_[n] = *(const short8*)&Bs[bi][R * BK + ph * 8];        \
            }                                                             \
            _Pragma("unroll")                                             \
            for (int m = 0; m < 4; m++)                                   \
                _Pragma("unroll")                                         \
                for (int n = 0; n < 4; n++)                               \
                    acc[m][n] = __builtin_amdgcn_mfma_f32_16x16x32_bf16(  \
                        af[m], bf_[n], acc[m][n], 0, 0, 0); } while (0)

        // prologue: stage tiles 0,1 (8 loads in flight)
        STAGE(0, 0);
        STAGE(1, 1);
        int cur = 0, nxt = 2;
        #pragma unroll 1
        for (int t = 0; t < NKT - 2; t++) {
            STAGE(t + 2, nxt);
            WAITV(8);            // t's 4 loads done; (t+1),(t+2)'s 8 in flight
            BARR;                // all waves: buf[cur] ready
            BODY(cur);
            BARR;                // all waves done reading buf[cur] -> reusable
            cur = (cur == 2) ? 0 : cur + 1;
            nxt = (nxt == 2) ? 0 : nxt + 1;
        }
        WAITV(4); BARR; BODY(cur); BARR;
        cur = (cur == 2) ? 0 : cur + 1;
        WAITV(0); BARR; BODY(cur); BARR;

        #undef STAGE
        #undef BODY

        // epilogue: atomicAdd (C/D: col=lane&15, row=(lane>>4)*4+j)
        #pragma unroll
        for (int m = 0; m < 4; m++) {
            #pragma unroll
            for (int j = 0; j < 4; j++) {
                int r = wm * 64 + m * 16 + g4 * 4 + j;
                int gr = m0 + r;
                if (gr < cnt) {
                    int entry = list[gr];
                    float s = scores2[entry];
                    float* orow = out + (size_t)(entry >> 1) * ODIM + n0 + wn * 64 + fr;
                    #pragma unroll
                    for (int n = 0; n < 4; n++)
                        atomicAdd(orow + n * 16, s * acc[m][n][j]);
                }
            }
        }
    }
}

extern "C" void kernel_launch(void* const* d_in, const int* in_sizes, int n_in,
                              void* d_out, int out_size, void* d_ws, size_t ws_size,
                              hipStream_t stream) {
    const float* x  = (const float*)d_in[0];
    const float* W  = (const float*)d_in[1];
    const float* b  = (const float*)d_in[2];
    const float* Wg = (const float*)d_in[3];
    const float* bg = (const float*)d_in[4];
    float* out = (float*)d_out;
    char* ws = (char*)d_ws;

    int*   counts  = (int*)(ws + CNT_OFF);
    float* scores2 = (float*)(ws + SC_OFF);
    int*   lists   = (int*)(ws + LIST_OFF);   // [8][NTOK]
    unsigned short* xh = (unsigned short*)(ws + XH_OFF);
    unsigned short* wh = (unsigned short*)(ws + WH_OFF);

    int n4w = NEXP * ODIM * DDIM / 4;
    k_cvtw<<<n4w / 256, 256, 0, stream>>>((const float4*)W, (ushort4*)wh, n4w, counts);

    k_gate<<<NTOK / 8, 256, 0, stream>>>(x, Wg, bg, b, out, scores2, lists, counts, xh);

    // persistent grid: 3 blocks/CU (48 KiB LDS) * 256 CUs = 768 (div by 8);
    // worst-case tiles sum_e ceil(c_e/128)*8 <= (128+7)*8 = 1080, stride loop.
    k_gemm<<<768, 256, 0, stream>>>(xh, wh, counts, lists, scores2, out);
}

// Round 8
// 166.895 us; speedup vs baseline: 1.3353x; 1.3353x over previous
//
#include <hip/hip_runtime.h>
#include <hip/hip_bf16.h>

// Problem constants (B=4, S=2048 -> 8192 tokens; D=O=1024; E=8; top-2)
#define NTOK 8192
#define DDIM 1024
#define ODIM 1024
#define NEXP 8
#define BK   32
#define NKT  (DDIM / BK)     // 32 K-tiles

typedef __attribute__((ext_vector_type(8))) short short8;
typedef __attribute__((ext_vector_type(4))) float f32x4;

// ---- workspace layout (bytes) ----
#define CNT_OFF   0u                               // 8 ints (per expert)
#define SC_OFF    (4u * 1024u)                     // 8192*2 floats
#define LIST_OFF  (128u * 1024u)                   // 8*8192 ints
#define XH_OFF    (1u << 20)                       // bf16 x, 16 MiB
#define WH_OFF    ((1u << 20) + 16u*1024u*1024u)   // bf16 W, 16 MiB

__device__ inline unsigned short f2bf(float f) {
    unsigned int u = __float_as_uint(f);
    unsigned int r = (u + 0x7FFFu + ((u >> 16) & 1u)) >> 16;   // RNE
    return (unsigned short)r;
}

__device__ inline void glds16(const unsigned short* g, unsigned short* l) {
    __builtin_amdgcn_global_load_lds(
        (const __attribute__((address_space(1))) unsigned int*)g,
        (__attribute__((address_space(3))) unsigned int*)l, 16, 0, 0);
}

// W fp32->bf16; block 0 also zeroes the per-expert counts (runs pre-gate)
__global__ void k_cvtw(const float4* __restrict__ src, ushort4* __restrict__ dst,
                       int n4, int* __restrict__ counts) {
    if (blockIdx.x == 0 && threadIdx.x < NEXP) counts[threadIdx.x] = 0;
    int i = blockIdx.x * blockDim.x + threadIdx.x;
    if (i >= n4) return;
    float4 v = src[i];
    ushort4 o;
    o.x = f2bf(v.x); o.y = f2bf(v.y); o.z = f2bf(v.z); o.w = f2bf(v.w);
    dst[i] = o;
}

// Gating: 1024 blocks x 8 tokens (2 per wave). No launch-bounds VGPR cap
// (round 5: forcing 128 VGPR spilled ~180MB scratch -> 107us). fp64
// dot+butterfly decides top-k; fp32 expf weights. 8 expert lists
// (entry = t*2+rank), block-aggregated scatter. Fused: bf16 x, and
// out init = s0*b0 + s1*b1 (gemm epilogue is atomicAdd).
__global__ __launch_bounds__(256) void k_gate(
    const float* __restrict__ x, const float* __restrict__ Wg,
    const float* __restrict__ bg, const float* __restrict__ b,
    float* __restrict__ out, float* __restrict__ scores2,
    int* __restrict__ lists, int* __restrict__ counts,
    unsigned short* __restrict__ xh)
{
    __shared__ unsigned char s_eid[16];     // 8 tokens * 2 entries
    const int tid = threadIdx.x, wave = tid >> 6, lane = tid & 63;
    const int tblk = blockIdx.x * 8;

    #pragma unroll 1
    for (int ti = 0; ti < 2; ti++) {
        const int t = tblk + wave * 2 + ti;
        const float* xr = x + (size_t)t * DDIM;
        float4 xv[4];
        #pragma unroll
        for (int i = 0; i < 4; i++)
            xv[i] = *(const float4*)&xr[lane * 4 + 256 * i];

        unsigned short* xhr = xh + (size_t)t * DDIM;
        #pragma unroll
        for (int i = 0; i < 4; i++) {
            ushort4 h;
            h.x = f2bf(xv[i].x); h.y = f2bf(xv[i].y);
            h.z = f2bf(xv[i].z); h.w = f2bf(xv[i].w);
            *(ushort4*)&xhr[lane * 4 + 256 * i] = h;
        }

        double lg[NEXP];
        #pragma unroll
        for (int e = 0; e < NEXP; e++) {
            const float* wr = Wg + (size_t)e * DDIM;
            double a = 0.0;
            #pragma unroll
            for (int i = 0; i < 4; i++) {
                float4 wv = *(const float4*)&wr[lane * 4 + 256 * i];
                a += (double)xv[i].x * (double)wv.x + (double)xv[i].y * (double)wv.y
                   + (double)xv[i].z * (double)wv.z + (double)xv[i].w * (double)wv.w;
            }
            #pragma unroll
            for (int off = 32; off > 0; off >>= 1) a += __shfl_xor(a, off);
            lg[e] = a + (double)bg[e];
        }

        int i0 = -1, i1 = -1;
        double best = -1e300, sec = -1e300;
        #pragma unroll
        for (int e = 0; e < NEXP; e++) {
            double v = lg[e];
            if (v > best) { sec = best; i1 = i0; best = v; i0 = e; }
            else if (v > sec) { sec = v; i1 = e; }
        }
        float sum = 0.f;
        #pragma unroll
        for (int e = 0; e < NEXP; e++) sum += expf((float)(lg[e] - best));
        float s0 = 1.f / sum;
        float s1 = expf((float)(sec - best)) / sum;

        if (lane == 0) {
            scores2[t * 2 + 0] = s0;
            scores2[t * 2 + 1] = s1;
            int le = (wave * 2 + ti) * 2;
            s_eid[le + 0] = (unsigned char)i0;
            s_eid[le + 1] = (unsigned char)i1;
        }

        const float* b0 = b + (size_t)i0 * ODIM;
        const float* b1 = b + (size_t)i1 * ODIM;
        float* orow = out + (size_t)t * ODIM;
        #pragma unroll
        for (int i = 0; i < 4; i++) {
            int o = lane * 4 + 256 * i;
            float4 v0 = *(const float4*)&b0[o];
            float4 v1 = *(const float4*)&b1[o];
            float4 r;
            r.x = s0 * v0.x + s1 * v1.x;
            r.y = s0 * v0.y + s1 * v1.y;
            r.z = s0 * v0.z + s1 * v1.z;
            r.w = s0 * v0.w + s1 * v1.w;
            *(float4*)&orow[o] = r;
        }
    }
    __syncthreads();

    // 8 owners; one global atomic per (block, expert)
    if (tid < NEXP) {
        int c = 0;
        #pragma unroll
        for (int j = 0; j < 16; j++) c += (s_eid[j] == tid);
        if (c) {
            int p = atomicAdd(&counts[tid], c);
            #pragma unroll
            for (int j = 0; j < 16; j++)
                if (s_eid[j] == tid)
                    lists[tid * NTOK + (p++)] = (tblk + (j >> 1)) * 2 + (j & 1);
        }
    }
}

// Grouped GEMM: BLOCK-PER-TILE (grid 1088 >= worst-case tiles, all resident
// at 32KB LDS -> no multi-tile serialization / no tail quantization).
// 128x128 tile, BK=32 double-buffered, one __syncthreads per K-step,
// XOR seg-swizzle (0 bank conflicts, verified round 3+). Epilogue atomicAdd
// (round 4 proved ~free); out was bias-initialized by k_gate.
__global__ __launch_bounds__(256, 4) void k_gemm(
    const unsigned short* __restrict__ xh, const unsigned short* __restrict__ wh,
    const int* __restrict__ counts, const int* __restrict__ lists,
    const float* __restrict__ scores2, float* __restrict__ out)
{
    __shared__ __align__(16) unsigned short As[2][128 * BK];
    __shared__ __align__(16) unsigned short Bs[2][128 * BK];

    // bijective chunked XCD swizzle (gridDim 1088 % 8 == 0)
    const int nwg = (int)gridDim.x;
    int bid = ((int)blockIdx.x & 7) * (nwg >> 3) + ((int)blockIdx.x >> 3);

    int e = -1, mt = 0, nt = 0, cnt = 0;
    #pragma unroll
    for (int ee = 0; ee < NEXP; ee++) {
        int c = counts[ee];
        int tiles = ((c + 127) >> 7) * 8;
        if (e < 0) {
            if (bid < tiles) { e = ee; mt = bid >> 3; nt = bid & 7; cnt = c; }
            else bid -= tiles;
        }
    }
    if (e < 0) return;

    const int m0 = mt * 128, n0 = nt * 128;
    const int* list = lists + e * NTOK;
    const unsigned short* whE = wh + (size_t)e * ODIM * DDIM;
    const int tid = threadIdx.x, wid = tid >> 6, lane = tid & 63;

    const int rl = lane >> 2;               // row within 16-row staging call
    const unsigned short* aS[2];
    const unsigned short* bS[2];
    int rb[2];
    #pragma unroll
    for (int i = 0; i < 2; i++) {
        int R = wid * 32 + i * 16 + rl;
        int sl = (lane & 3) ^ ((R >> 1) & 3);       // inverse-swizzled seg
        int g = m0 + R; if (g >= cnt) g = cnt - 1;
        aS[i] = xh + (size_t)(list[g] >> 1) * DDIM + sl * 8;
        bS[i] = whE + (size_t)(n0 + R) * DDIM + sl * 8;
        rb[i] = (wid * 32 + i * 16) * BK;
    }

    const int wm = wid >> 1, wn = wid & 1;
    const int fr = lane & 15, g4 = lane >> 4;

    f32x4 acc[4][4];
    #pragma unroll
    for (int m = 0; m < 4; m++)
        #pragma unroll
        for (int n = 0; n < 4; n++)
            acc[m][n] = (f32x4){0.f, 0.f, 0.f, 0.f};

    #pragma unroll
    for (int i = 0; i < 2; i++) {
        glds16(aS[i], &As[0][rb[i]]);
        glds16(bS[i], &Bs[0][rb[i]]);
    }

    int buf = 0;
    #pragma unroll 1
    for (int t = 0; t < NKT; t++) {
        __syncthreads();                 // stage(t) landed (vmcnt drain)
        if (t + 1 < NKT) {
            const int k0 = (t + 1) * BK;
            #pragma unroll
            for (int i = 0; i < 2; i++) {
                glds16(aS[i] + k0, &As[buf ^ 1][rb[i]]);
                glds16(bS[i] + k0, &Bs[buf ^ 1][rb[i]]);
            }
        }
        short8 af[4], bf_[4];
        #pragma unroll
        for (int m = 0; m < 4; m++) {
            int R = wm * 64 + m * 16 + fr;
            int ph = g4 ^ ((R >> 1) & 3);
            af[m] = *(const short8*)&As[buf][R * BK + ph * 8];
        }
        #pragma unroll
        for (int n = 0; n < 4; n++) {
            int R = wn * 64 + n * 16 + fr;
            int ph = g4 ^ ((R >> 1) & 3);
            bf_[n] = *(const short8*)&Bs[buf][R * BK + ph * 8];
        }
        #pragma unroll
        for (int m = 0; m < 4; m++)
            #pragma unroll
            for (int n = 0; n < 4; n++)
                acc[m][n] = __builtin_amdgcn_mfma_f32_16x16x32_bf16(
                    af[m], bf_[n], acc[m][n], 0, 0, 0);
        buf ^= 1;
    }

    // epilogue: atomicAdd (C/D: col=lane&15, row=(lane>>4)*4+j)
    #pragma unroll
    for (int m = 0; m < 4; m++) {
        #pragma unroll
        for (int j = 0; j < 4; j++) {
            int r = wm * 64 + m * 16 + g4 * 4 + j;
            int gr = m0 + r;
            if (gr < cnt) {
                int entry = list[gr];
                float s = scores2[entry];
                float* orow = out + (size_t)(entry >> 1) * ODIM + n0 + wn * 64 + fr;
                #pragma unroll
                for (int n = 0; n < 4; n++)
                    atomicAdd(orow + n * 16, s * acc[m][n][j]);
            }
        }
    }
}

extern "C" void kernel_launch(void* const* d_in, const int* in_sizes, int n_in,
                              void* d_out, int out_size, void* d_ws, size_t ws_size,
                              hipStream_t stream) {
    const float* x  = (const float*)d_in[0];
    const float* W  = (const float*)d_in[1];
    const float* b  = (const float*)d_in[2];
    const float* Wg = (const float*)d_in[3];
    const float* bg = (const float*)d_in[4];
    float* out = (float*)d_out;
    char* ws = (char*)d_ws;

    int*   counts  = (int*)(ws + CNT_OFF);
    float* scores2 = (float*)(ws + SC_OFF);
    int*   lists   = (int*)(ws + LIST_OFF);   // [8][NTOK]
    unsigned short* xh = (unsigned short*)(ws + XH_OFF);
    unsigned short* wh = (unsigned short*)(ws + WH_OFF);

    int n4w = NEXP * ODIM * DDIM / 4;
    k_cvtw<<<n4w / 256, 256, 0, stream>>>((const float4*)W, (ushort4*)wh, n4w, counts);

    k_gate<<<NTOK / 8, 256, 0, stream>>>(x, Wg, bg, b, out, scores2, lists, counts, xh);

    // block-per-tile: worst case sum_e ceil(c_e/128)*8 <= 1080 <= 1088;
    // 1088 blocks all co-resident (32KB LDS -> 5 blocks/CU) -> single round.
    k_gemm<<<1088, 256, 0, stream>>>(xh, wh, counts, lists, scores2, out);
}